// Round 4
// baseline (278.626 us; speedup 1.0000x reference)
//
#include <hip/hip_runtime.h>

// Gridding R4: two-pass binning with PAYLOAD buckets (SoA), all global
// traffic coalesced.
//   Phase 1: one block per (batch, 2048-pt chunk). Points are staged into
//     per-x-slab LDS buckets (scaled coords, SoA: 3 x 16KiB), then flushed
//     to global buckets with fully coalesced dword stores. No scattered
//     global writes, no sub-dword stores.
//   Phase 2: one block per (batch, x-slab). Reads its bucket as a DENSE
//     coalesced stream (slot t -> global index base+t), accumulates into a
//     64 KiB LDS sub-grid, flushes coalesced. Exclusive ownership: every
//     output cell written exactly once -> no memset, no global atomics.

#define NPTS   65536
#define NCHUNK 32
#define CHSZ   2048
#define NSLAB  16
#define SLABW  4
#define CCAP   256                 // per (slab,chunk) capacity; mean~160, +8 sigma
#define SLOTS  (NCHUNK * CCAP)     // 8192 slots per bucket
#define SUBN   (SLABW * 64 * 64)   // 16384 floats = 64 KiB

__global__ __launch_bounds__(512) void p1_bin(
    const float* __restrict__ pt,
    float* __restrict__ gx, float* __restrict__ gy, float* __restrict__ gz,
    int* __restrict__ bcnt)            // [B*16][NCHUNK]
{
    __shared__ float sxl[NSLAB * CCAP];
    __shared__ float syl[NSLAB * CCAP];
    __shared__ float szl[NSLAB * CCAP];
    __shared__ int   cnt[NSLAB];
    if (threadIdx.x < NSLAB) cnt[threadIdx.x] = 0;
    __syncthreads();

    const int blk = blockIdx.x;         // B*NCHUNK
    const int b = blk >> 5;
    const int c = blk & 31;
    const float* p = pt + ((size_t)b * NPTS + (size_t)c * CHSZ) * 3;

    #pragma unroll
    for (int k = 0; k < CHSZ / 512; ++k) {
        int li = k * 512 + threadIdx.x;
        float px = p[3 * li + 0] * 32.0f;   // *32 is exact in fp32
        float py = p[3 * li + 1] * 32.0f;
        float pz = p[3 * li + 2] * 32.0f;
        if (fabsf(px) + fabsf(py) + fabsf(pz) == 0.0f) continue;  // nz_mask
        int ix = (int)floorf(px) + 32;      // in [0,63] for inputs in [-1,1)
        if ((unsigned)ix > 63u) continue;
        int s0 = ix >> 2;
        int pos = atomicAdd(&cnt[s0], 1);
        if (pos < CCAP) {
            int a = s0 * CCAP + pos;
            sxl[a] = px; syl[a] = py; szl[a] = pz;
        }
        if ((ix & 3) == 3 && ix < 63) {     // x+1 plane lives in next slab
            int pos1 = atomicAdd(&cnt[s0 + 1], 1);
            if (pos1 < CCAP) {
                int a = (s0 + 1) * CCAP + pos1;
                sxl[a] = px; syl[a] = py; szl[a] = pz;
            }
        }
    }
    __syncthreads();

    // Coalesced flush of all slots (garbage past count is skipped by p2).
    // dest for slab s, entry e: ((b*16+s)*NCHUNK + c)*CCAP + e
    #pragma unroll
    for (int i = threadIdx.x; i < NSLAB * CCAP; i += 512) {
        int s = i >> 8, e = i & 255;
        size_t d = ((size_t)((b * NSLAB + s) * NCHUNK + c)) * CCAP + e;
        gx[d] = sxl[i]; gy[d] = syl[i]; gz[d] = szl[i];
    }
    if (threadIdx.x < NSLAB)
        bcnt[(b * NSLAB + threadIdx.x) * NCHUNK + c] = min(cnt[threadIdx.x], CCAP);
}

__global__ __launch_bounds__(1024) void p2_accum(
    const float* __restrict__ gx, const float* __restrict__ gy,
    const float* __restrict__ gz, const int* __restrict__ bcnt,
    float* __restrict__ out)
{
    __shared__ float g[SUBN];
    const int bs = blockIdx.x;          // b*16 + s
    const int b  = bs >> 4;
    const int s  = bs & 15;
    const int x0 = s * SLABW;

    float4* g4 = (float4*)g;
    #pragma unroll
    for (int i = threadIdx.x; i < SUBN / 4; i += 1024)
        g4[i] = make_float4(0.f, 0.f, 0.f, 0.f);
    __syncthreads();

    const size_t base = (size_t)bs * SLOTS;   // bucket layout == slot order
    const int* myc = bcnt + bs * NCHUNK;

    #pragma unroll
    for (int t = threadIdx.x; t < SLOTS; t += 1024) {
        int c = t >> 8;                  // CCAP = 256
        int pos = t & 255;
        if (pos >= myc[c]) continue;     // wave-mostly-uniform (256-slot runs)

        float px = gx[base + t];         // fully coalesced dword streams
        float py = gy[base + t];
        float pz = gz[base + t];

        float lx = floorf(px), ly = floorf(py), lz = floorf(pz);
        float fx = px - lx,    fy = py - ly,    fz = pz - lz;
        int ix = (int)lx + 32, iy = (int)ly + 32, iz = (int)lz + 32;

        float wx[2] = {1.0f - fx, fx};
        float wy[2] = {1.0f - fy, fy};
        float wz[2] = {1.0f - fz, fz};

        #pragma unroll
        for (int di = 0; di < 2; ++di) {
            int xl = ix + di - x0;                 // slab-local x
            if ((unsigned)xl >= SLABW) continue;
            #pragma unroll
            for (int dj = 0; dj < 2; ++dj) {
                int yy = iy + dj;
                if ((unsigned)yy >= 64u) continue;
                float wxy = wx[di] * wy[dj];
                int lbase = (xl * 64 + yy) * 64;
                #pragma unroll
                for (int dk = 0; dk < 2; ++dk) {
                    int zz = iz + dk;
                    if ((unsigned)zz >= 64u) continue;
                    atomicAdd(&g[lbase + zz], wxy * wz[dk]);  // ds_add_f32
                }
            }
        }
    }
    __syncthreads();

    float4* o4 = (float4*)(out + ((size_t)b * 64 + x0) * 4096);
    #pragma unroll
    for (int i = threadIdx.x; i < SUBN / 4; i += 1024)
        o4[i] = g4[i];
}

// ---- Fallback (R2 exclusive-slab redundant scan) if workspace too small.
__global__ __launch_bounds__(1024) void gridding_slab(
    const float* __restrict__ pt, float* __restrict__ out)
{
    __shared__ float lds[SUBN];
    const int blk = blockIdx.x;
    const int b   = blk >> 4;
    const int x0  = (blk & 15) * SLABW;
    float4* l4 = (float4*)lds;
    #pragma unroll
    for (int i = threadIdx.x; i < SUBN / 4; i += 1024)
        l4[i] = make_float4(0.f, 0.f, 0.f, 0.f);
    __syncthreads();
    const float* p = pt + (size_t)b * NPTS * 3;
    for (int it = 0; it < NPTS / 1024; ++it) {
        int i = it * 1024 + threadIdx.x;
        float px = p[3 * i + 0] * 32.0f;
        float py = p[3 * i + 1] * 32.0f;
        float pz = p[3 * i + 2] * 32.0f;
        if (fabsf(px) + fabsf(py) + fabsf(pz) == 0.0f) continue;
        float lx = floorf(px), ly = floorf(py), lz = floorf(pz);
        float fx = px - lx, fy = py - ly, fz = pz - lz;
        int ix = (int)lx + 32, iy = (int)ly + 32, iz = (int)lz + 32;
        float wx[2] = {1.0f - fx, fx};
        float wy[2] = {1.0f - fy, fy};
        float wz[2] = {1.0f - fz, fz};
        #pragma unroll
        for (int di = 0; di < 2; ++di) {
            int xl = (ix + di) - x0;
            if ((unsigned)xl >= SLABW) continue;
            #pragma unroll
            for (int dj = 0; dj < 2; ++dj) {
                int yy = iy + dj;
                if ((unsigned)yy >= 64u) continue;
                float wxy = wx[di] * wy[dj];
                int base = (xl * 64 + yy) * 64;
                #pragma unroll
                for (int dk = 0; dk < 2; ++dk) {
                    int zz = iz + dk;
                    if ((unsigned)zz >= 64u) continue;
                    atomicAdd(&lds[base + zz], wxy * wz[dk]);
                }
            }
        }
    }
    __syncthreads();
    float4* o4 = (float4*)(out + ((size_t)b * 64 + x0) * 4096);
    #pragma unroll
    for (int i = threadIdx.x; i < SUBN / 4; i += 1024)
        o4[i] = l4[i];
}

extern "C" void kernel_launch(void* const* d_in, const int* in_sizes, int n_in,
                              void* d_out, int out_size, void* d_ws, size_t ws_size,
                              hipStream_t stream) {
    const float* pt = (const float*)d_in[0];
    float* out = (float*)d_out;
    const int B = (in_sizes[0] / 3) / NPTS;   // 64

    const size_t nbuck = (size_t)B * NSLAB;           // 1024
    const size_t arr   = nbuck * SLOTS;               // 8.39M floats each
    const size_t need  = 3 * arr * sizeof(float) + nbuck * NCHUNK * sizeof(int);

    if (ws_size >= need) {
        float* gx = (float*)d_ws;
        float* gy = gx + arr;
        float* gz = gy + arr;
        int* bcnt = (int*)(gz + arr);
        p1_bin<<<B * NCHUNK, 512, 0, stream>>>(pt, gx, gy, gz, bcnt);
        p2_accum<<<(int)nbuck, 1024, 0, stream>>>(gx, gy, gz, bcnt, out);
    } else {
        gridding_slab<<<B * NSLAB, 1024, 0, stream>>>(pt, out);
    }
}

// Round 5
// 190.140 us; speedup vs baseline: 1.4654x; 1.4654x over previous
//
#include <hip/hip_runtime.h>

// Gridding R5: R4's binning (p1 unchanged) + packed u64 LDS atomics in p2.
//   Key insight from R3/R4 counters: p2 is bound by the LDS atomic pipe
//   (~3.25 cyc per lane-level ds_add, 33.5M lane-atomics). A point's two
//   z-corners are adjacent cells -> pack both 32-bit fixed-point weights
//   into ONE ds_add_u64 (scale 2^18, no cross-carry: cell sums << 16384).
//   Odd-z pairs are 8B-misaligned, so a second shifted accumulator B
//   (B[2j],B[2j+1] <-> cells 2j+1,2j+2) receives them; parity selects the
//   offset branchlessly. 8 f32 atomics/point -> 4 u64 atomics/point.
//   LDS doubles per cell -> slab halves to 2 x-planes; 2 p2 blocks share
//   one R4 bucket stream (coalesced, L2/L3-resident).

#define NPTS   65536
#define NCHUNK 32
#define CHSZ   2048
#define NSLAB  16                  // p1 bucket slabs (4 planes, as R4)
#define SLABW  4
#define CCAP   256
#define SLOTS  (NCHUNK * CCAP)     // 8192 slots per bucket
#define ACCN   16384               // 2 planes * 64 * 64 u32 per accumulator
#define QSCALE 262144.0f           // 2^18
#define QINV   (1.0f / 262144.0f)

// ---------------- Phase 1: identical to R4 ----------------
__global__ __launch_bounds__(512) void p1_bin(
    const float* __restrict__ pt,
    float* __restrict__ gx, float* __restrict__ gy, float* __restrict__ gz,
    int* __restrict__ bcnt)
{
    __shared__ float sxl[NSLAB * CCAP];
    __shared__ float syl[NSLAB * CCAP];
    __shared__ float szl[NSLAB * CCAP];
    __shared__ int   cnt[NSLAB];
    if (threadIdx.x < NSLAB) cnt[threadIdx.x] = 0;
    __syncthreads();

    const int blk = blockIdx.x;
    const int b = blk >> 5;
    const int c = blk & 31;
    const float* p = pt + ((size_t)b * NPTS + (size_t)c * CHSZ) * 3;

    #pragma unroll
    for (int k = 0; k < CHSZ / 512; ++k) {
        int li = k * 512 + threadIdx.x;
        float px = p[3 * li + 0] * 32.0f;
        float py = p[3 * li + 1] * 32.0f;
        float pz = p[3 * li + 2] * 32.0f;
        if (fabsf(px) + fabsf(py) + fabsf(pz) == 0.0f) continue;
        int ix = (int)floorf(px) + 32;
        if ((unsigned)ix > 63u) continue;
        int s0 = ix >> 2;
        int pos = atomicAdd(&cnt[s0], 1);
        if (pos < CCAP) {
            int a = s0 * CCAP + pos;
            sxl[a] = px; syl[a] = py; szl[a] = pz;
        }
        if ((ix & 3) == 3 && ix < 63) {
            int pos1 = atomicAdd(&cnt[s0 + 1], 1);
            if (pos1 < CCAP) {
                int a = (s0 + 1) * CCAP + pos1;
                sxl[a] = px; syl[a] = py; szl[a] = pz;
            }
        }
    }
    __syncthreads();

    #pragma unroll
    for (int i = threadIdx.x; i < NSLAB * CCAP; i += 512) {
        int s = i >> 8, e = i & 255;
        size_t d = ((size_t)((b * NSLAB + s) * NCHUNK + c)) * CCAP + e;
        gx[d] = sxl[i]; gy[d] = syl[i]; gz[d] = szl[i];
    }
    if (threadIdx.x < NSLAB)
        bcnt[(b * NSLAB + threadIdx.x) * NCHUNK + c] = min(cnt[threadIdx.x], CCAP);
}

// ---------------- Phase 2: 2-plane sub-slab, packed u64 LDS atomics -------
__global__ __launch_bounds__(1024) void p2_accum(
    const float* __restrict__ gx, const float* __restrict__ gy,
    const float* __restrict__ gz, const int* __restrict__ bcnt,
    float* __restrict__ out)
{
    // S[0..ACCN)      = A: cell (xl,y,z) at (xl*64+y)*64+z   (z-even u64 pairs)
    // S[ACCN..2*ACCN) = B: index (cb + z-1) <-> shifted pairs (z-odd u64 pairs)
    __shared__ unsigned int S[2 * ACCN];

    const int pb = blockIdx.x >> 1;     // parent bucket (b*16 + s)
    const int h  = blockIdx.x & 1;      // which half of the 4-wide slab
    const int b  = pb >> 4;
    const int s  = pb & 15;
    const int x0 = s * SLABW + h * 2;   // my 2 planes: x0, x0+1

    uint4* s4 = (uint4*)S;
    #pragma unroll
    for (int i = threadIdx.x; i < (2 * ACCN) / 4; i += 1024)
        s4[i] = make_uint4(0u, 0u, 0u, 0u);
    __syncthreads();

    const size_t base = (size_t)pb * SLOTS;
    const int* myc = bcnt + pb * NCHUNK;

    #pragma unroll
    for (int t = threadIdx.x; t < SLOTS; t += 1024) {
        int c = t >> 8;                 // CCAP = 256
        int pos = t & 255;
        if (pos >= myc[c]) continue;

        float px = gx[base + t];
        float py = gy[base + t];
        float pz = gz[base + t];

        float lx = floorf(px), ly = floorf(py), lz = floorf(pz);
        float fx = px - lx,    fy = py - ly,    fz = pz - lz;
        int ix = (int)lx + 32, iy = (int)ly + 32, iz = (int)lz + 32;
        if ((unsigned)iz > 63u) continue;   // defensive

        float wx[2] = {1.0f - fx, fx};
        float wy[2] = {1.0f - fy, fy};
        float wz0 = 1.0f - fz, wz1 = fz;

        // z-pair target offset, branchless on parity:
        //   even z: A at cb+iz ; odd z: B at ACCN + cb + iz - 1  (both 8B-aligned)
        const int odd = iz & 1;
        const int zoff = odd ? (ACCN + iz - 1) : iz;
        const bool hi_ok = (iz != 63);      // cell iz+1==64 is OOB -> add 0

        #pragma unroll
        for (int di = 0; di < 2; ++di) {
            int xl = ix + di - x0;          // sub-slab-local x
            if ((unsigned)xl >= 2u) continue;
            #pragma unroll
            for (int dj = 0; dj < 2; ++dj) {
                int yy = iy + dj;
                if ((unsigned)yy >= 64u) continue;
                float wxy = wx[di] * wy[dj];
                unsigned int q0 = __float2uint_rn(wxy * wz0 * QSCALE);
                unsigned int q1 = hi_ok ? __float2uint_rn(wxy * wz1 * QSCALE) : 0u;
                int cb = (xl * 64 + yy) * 64;
                unsigned long long pk =
                    (unsigned long long)q0 | ((unsigned long long)q1 << 32);
                atomicAdd((unsigned long long*)&S[cb + zoff], pk);  // ds_add_u64
            }
        }
    }
    __syncthreads();

    // Flush: cell i (= (xl*64+y)*64+z) = A[i] + (z>0 ? B[i-1] : 0), dequant.
    float* o = out + ((size_t)b * 64 + x0) * 4096;
    #pragma unroll
    for (int i = threadIdx.x; i < 2 * 4096; i += 1024) {
        int z = i & 63;
        unsigned int v = S[i] + (z ? S[ACCN + i - 1] : 0u);
        o[i] = (float)v * QINV;
    }
}

// ---- Fallback (R2 exclusive-slab redundant scan) if workspace too small.
__global__ __launch_bounds__(1024) void gridding_slab(
    const float* __restrict__ pt, float* __restrict__ out)
{
    __shared__ float lds[SLABW * 64 * 64];
    const int blk = blockIdx.x;
    const int b   = blk >> 4;
    const int x0  = (blk & 15) * SLABW;
    float4* l4 = (float4*)lds;
    #pragma unroll
    for (int i = threadIdx.x; i < (SLABW * 64 * 64) / 4; i += 1024)
        l4[i] = make_float4(0.f, 0.f, 0.f, 0.f);
    __syncthreads();
    const float* p = pt + (size_t)b * NPTS * 3;
    for (int it = 0; it < NPTS / 1024; ++it) {
        int i = it * 1024 + threadIdx.x;
        float px = p[3 * i + 0] * 32.0f;
        float py = p[3 * i + 1] * 32.0f;
        float pz = p[3 * i + 2] * 32.0f;
        if (fabsf(px) + fabsf(py) + fabsf(pz) == 0.0f) continue;
        float lx = floorf(px), ly = floorf(py), lz = floorf(pz);
        float fx = px - lx, fy = py - ly, fz = pz - lz;
        int ix = (int)lx + 32, iy = (int)ly + 32, iz = (int)lz + 32;
        float wx[2] = {1.0f - fx, fx};
        float wy[2] = {1.0f - fy, fy};
        float wz[2] = {1.0f - fz, fz};
        #pragma unroll
        for (int di = 0; di < 2; ++di) {
            int xl = (ix + di) - x0;
            if ((unsigned)xl >= SLABW) continue;
            #pragma unroll
            for (int dj = 0; dj < 2; ++dj) {
                int yy = iy + dj;
                if ((unsigned)yy >= 64u) continue;
                float wxy = wx[di] * wy[dj];
                int basei = (xl * 64 + yy) * 64;
                #pragma unroll
                for (int dk = 0; dk < 2; ++dk) {
                    int zz = iz + dk;
                    if ((unsigned)zz >= 64u) continue;
                    atomicAdd(&lds[basei + zz], wxy * wz[dk]);
                }
            }
        }
    }
    __syncthreads();
    float4* o4 = (float4*)(out + ((size_t)b * 64 + x0) * 4096);
    #pragma unroll
    for (int i = threadIdx.x; i < (SLABW * 64 * 64) / 4; i += 1024)
        o4[i] = l4[i];
}

extern "C" void kernel_launch(void* const* d_in, const int* in_sizes, int n_in,
                              void* d_out, int out_size, void* d_ws, size_t ws_size,
                              hipStream_t stream) {
    const float* pt = (const float*)d_in[0];
    float* out = (float*)d_out;
    const int B = (in_sizes[0] / 3) / NPTS;   // 64

    const size_t nbuck = (size_t)B * NSLAB;           // 1024
    const size_t arr   = nbuck * SLOTS;
    const size_t need  = 3 * arr * sizeof(float) + nbuck * NCHUNK * sizeof(int);

    if (ws_size >= need) {
        float* gx = (float*)d_ws;
        float* gy = gx + arr;
        float* gz = gy + arr;
        int* bcnt = (int*)(gz + arr);
        p1_bin<<<B * NCHUNK, 512, 0, stream>>>(pt, gx, gy, gz, bcnt);
        p2_accum<<<(int)(nbuck * 2), 1024, 0, stream>>>(gx, gy, gz, bcnt, out);
    } else {
        gridding_slab<<<B * NSLAB, 1024, 0, stream>>>(pt, out);
    }
}